// Round 6
// baseline (126.239 us; speedup 1.0000x reference)
//
#include <hip/hip_runtime.h>
#include <hip/hip_bf16.h>

// ChebyKANLinear: y[b,j] = sum_i sum_k T_k(tanh(x[b,i])) * C[i,j,k]
// GEMM: M=16384, N=512, K=4608 (kflat = k*512 + i).
// v5: wave tile 64x64 (8 waves = 2m x 4n; BM=128, BN=256) -> B-frag reuse 4x,
//     per-CU LDS read demand halves vs v4. A basis in registers (96 reg state).
//     T4: 3-buffer staging with counted vmcnt (never 0) + raw s_barrier ->
//     loads stay in flight across barriers. T5 setprio around MFMA cluster.

typedef __bf16 bf16x8 __attribute__((ext_vector_type(8)));
typedef float  f32x4  __attribute__((ext_vector_type(4)));

#define DIM  512
#define KDEG 9
#define BM   128
#define BN   256
#define NIC  16
#define SLAB (4 * DIM * 8)   // 16384 bf16 per kstep slab of W2

// ---- pack kernel: C[i][j][k] -> W2[(k*16+ic)][s][j][e]  (i = ic*32+s*8+e) ----
__global__ void pack_w_kernel(const float* __restrict__ coeffs,
                              __bf16* __restrict__ W2) {
    int t  = blockIdx.x * blockDim.x + threadIdx.x;   // 32768 threads
    int j  = t & (DIM - 1);
    int s  = (t >> 9) & 3;
    int ic = t >> 11;

    bf16x8 v[KDEG];
#pragma unroll
    for (int e = 0; e < 8; ++e) {
        int i = ic * 32 + s * 8 + e;
        const float* src = coeffs + ((size_t)i * DIM + j) * KDEG;
#pragma unroll
        for (int k = 0; k < KDEG; ++k)
            v[k][e] = (__bf16)src[k];
    }
#pragma unroll
    for (int k = 0; k < KDEG; ++k) {
        size_t off = (size_t)(k * 16 + ic) * SLAB + ((size_t)s * DIM + j) * 8;
        *reinterpret_cast<bf16x8*>(W2 + off) = v[k];
    }
}

// ---------------- fused Chebyshev-basis + MFMA GEMM -----------------------------
__global__ __launch_bounds__(512, 2) void cheby_gemm_kernel(
    const float* __restrict__ x,
    const __bf16* __restrict__ W2,
    float* __restrict__ out)
{
    // 3 staging buffers, slot-major: elem (s*BN + jl)*8 ; 16KB each
    __shared__ __bf16 Bl[3][4 * BN * 8];

    const int tid  = threadIdx.x;
    const int lane = tid & 63;
    const int wid  = tid >> 6;     // 0..7
    const int wr   = wid >> 2;     // 0..1  m-group (64 rows)
    const int wc   = wid & 3;      // 0..3  n-group (64 cols)
    const int l15  = lane & 15;
    const int l4   = lane >> 4;    // 0..3
    const int bm   = blockIdx.y * BM;
    const int bn   = blockIdx.x * BN;

    // staging: thread t covers two 16B chunks: (s=t>>8, jl=t&255) and (s+2, jl)
    const size_t soffA = ((size_t)((tid >> 8) * DIM + bn + (tid & 255))) * 8;
    const size_t soffB = soffA + (size_t)2 * DIM * 8;

#define STAGE(slabidx, buf)                                                         \
    { const __bf16* sp_ = W2 + (size_t)(slabidx) * SLAB;                            \
      __builtin_amdgcn_global_load_lds(sp_ + soffA, &Bl[(buf)][0] + tid * 8, 16, 0, 0); \
      __builtin_amdgcn_global_load_lds(sp_ + soffB, &Bl[(buf)][4096] + tid * 8, 16, 0, 0); }

    // A: 4 row-frags per wave (rows wr*64 + mf*16 + l15), lane slot l4
    const float* xr0 = x + (size_t)(bm + wr * 64 + l15) * DIM + l4 * 8;

    // B frag read base: elem (l4*BN + wc*64 + nf*16 + l15)*8
    const int boff = (l4 * BN + wc * 64 + l15) * 8;

    f32x4 acc[4][4] = {};

    bf16x8 aone;
#pragma unroll
    for (int e = 0; e < 8; ++e) aone[e] = (__bf16)1.0f;

    // prologue: stage steps (0,0) and (0,1)
    STAGE(0, 0);          // slab k=0,ic=0 -> buf 0
    STAGE(16, 1);         // slab k=1,ic=0 -> buf 1

    for (int ic = 0; ic < NIC; ++ic) {
        // ---- x loads + tanh + recurrence init for this ic ----
        float t2[4][8], Tk[4][8], Tm[4][8];
#pragma unroll
        for (int mf = 0; mf < 4; ++mf) {
            f32x4 xa = *reinterpret_cast<const f32x4*>(xr0 + mf * 16 * DIM + ic * 32);
            f32x4 xb = *reinterpret_cast<const f32x4*>(xr0 + mf * 16 * DIM + ic * 32 + 4);
#pragma unroll
            for (int e = 0; e < 8; ++e) {
                float xv = (e < 4) ? xa[e] : xb[e - 4];
                float p  = __builtin_amdgcn_exp2f(xv * 2.8853900817779268f);
                float t  = 1.0f - 2.0f * __builtin_amdgcn_rcpf(p + 1.0f);
                Tk[mf][e] = t;          // T_1
                t2[mf][e] = t + t;
                Tm[mf][e] = 1.0f;       // T_0
            }
        }

        const int icn = (ic + 1) & (NIC - 1);   // wraps at tail -> dummy stage, data unused

#pragma unroll
        for (int k = 0; k < KDEG; ++k) {
            // counted wait: own staging loads for THIS step retired; later ones in flight.
            // issue order per ic: [stage(ic,0)]2 [stage(ic,1)]2 [x]8 [stage(ic,2)]2 ...
            if (k < 2) { asm volatile("s_waitcnt vmcnt(10)" ::: "memory"); }
            else       { asm volatile("s_waitcnt vmcnt(2)"  ::: "memory"); }
            __builtin_amdgcn_s_barrier();

            // stage step+2 into buffer (k+2)%3
            {
                const int nk  = (k < 7) ? k + 2 : k - 7;
                const int nic = (k < 7) ? ic : icn;
                STAGE(nk * 16 + nic, (k + 2) % 3);
            }

            // A fragments for this k
            bf16x8 af[4];
            if (k == 0) {
#pragma unroll
                for (int mf = 0; mf < 4; ++mf) af[mf] = aone;   // T_0 = 1
            } else {
#pragma unroll
                for (int mf = 0; mf < 4; ++mf)
#pragma unroll
                    for (int e = 0; e < 8; ++e)
                        af[mf][e] = (__bf16)Tk[mf][e];
                if (k < KDEG - 1) {
#pragma unroll
                    for (int mf = 0; mf < 4; ++mf)
#pragma unroll
                        for (int e = 0; e < 8; ++e) {
                            float Tn = __builtin_fmaf(t2[mf][e], Tk[mf][e], -Tm[mf][e]);
                            Tm[mf][e] = Tk[mf][e];
                            Tk[mf][e] = Tn;
                        }
                }
            }

            // B frags (conflict-free slot-major) + 16 MFMA
            const __bf16* bb = &Bl[k % 3][0] + boff;
            __builtin_amdgcn_s_setprio(1);
#pragma unroll
            for (int nf = 0; nf < 4; ++nf) {
                bf16x8 b = *reinterpret_cast<const bf16x8*>(bb + nf * 16 * 8);
#pragma unroll
                for (int mf = 0; mf < 4; ++mf)
                    acc[mf][nf] = __builtin_amdgcn_mfma_f32_16x16x32_bf16(
                        af[mf], b, acc[mf][nf], 0, 0, 0);
            }
            __builtin_amdgcn_s_setprio(0);
        }
    }

    // ---- epilogue: C/D layout col=lane&15, row=(lane>>4)*4+r ----
#pragma unroll
    for (int mf = 0; mf < 4; ++mf)
#pragma unroll
        for (int r = 0; r < 4; ++r) {
            const int row = bm + wr * 64 + mf * 16 + l4 * 4 + r;
            float* orow = out + (size_t)row * DIM + bn + wc * 64 + l15;
#pragma unroll
            for (int nf = 0; nf < 4; ++nf)
                orow[nf * 16] = acc[mf][nf][r];
        }
#undef STAGE
}

extern "C" void kernel_launch(void* const* d_in, const int* in_sizes, int n_in,
                              void* d_out, int out_size, void* d_ws, size_t ws_size,
                              hipStream_t stream) {
    const float* x      = (const float*)d_in[0];   // (16384, 512)
    const float* coeffs = (const float*)d_in[1];   // (512, 512, 9)
    float* out          = (float*)d_out;           // (16384, 512)
    __bf16* W2          = (__bf16*)d_ws;           // 144*16384 bf16 = 4.7MB

    pack_w_kernel<<<(DIM * 64) / 256, 256, 0, stream>>>(coeffs, W2);

    // grid = (N/BN, M/BM) = (2, 128) = 256 blocks = 1 per CU
    cheby_gemm_kernel<<<dim3(DIM / BN, 16384 / BM), 512, 0, stream>>>(x, W2, out);
}

// Round 9
// 102.961 us; speedup vs baseline: 1.2261x; 1.2261x over previous
//
#include <hip/hip_runtime.h>
#include <hip/hip_bf16.h>

// ChebyKANLinear: y[b,j] = sum_i sum_k T_k(tanh(x[b,i])) * C[i,j,k]
// GEMM: M=16384, N=512, K=4608 (kflat = k*512 + i).
// v8 = v7 architecture (barrier-free, no LDS, B in registers from L2-resident
//     W2, wave tile 64x128, 1 wave/SIMD, f32 recurrence + bf16 operands)
//     with the ic-boundary buffer-parity bug FIXED: 3 rotating register
//     buffer sets (cs = k%3; 9 % 3 == 0 -> rotation self-aligned across ic),
//     prefetch depth 2 (~1240 cyc ahead of use).

typedef __bf16 bf16x8 __attribute__((ext_vector_type(8)));
typedef float  f32x4  __attribute__((ext_vector_type(4)));

#define DIM  512
#define KDEG 9
#define NIC  16
#define SLAB (4 * DIM * 8)   // 16384 bf16 per (k,ic) slab

// ---- pack: C[i][j][k] -> W2[(k*16+ic)][s][j][e] (bf16), i = ic*32 + s*8 + e ----
__global__ void pack_w_kernel(const float* __restrict__ coeffs,
                              __bf16* __restrict__ W2) {
    int t  = blockIdx.x * blockDim.x + threadIdx.x;   // 32768 threads
    int j  = t & (DIM - 1);
    int s  = (t >> 9) & 3;
    int ic = t >> 11;

    bf16x8 v[KDEG];
#pragma unroll
    for (int e = 0; e < 8; ++e) {
        int i = ic * 32 + s * 8 + e;
        const float* src = coeffs + ((size_t)i * DIM + j) * KDEG;
#pragma unroll
        for (int k = 0; k < KDEG; ++k)
            v[k][e] = (__bf16)src[k];
    }
#pragma unroll
    for (int k = 0; k < KDEG; ++k) {
        size_t off = (size_t)(k * 16 + ic) * SLAB + ((size_t)s * DIM + j) * 8;
        *reinterpret_cast<bf16x8*>(W2 + off) = v[k];
    }
}

// ---------------- fused Chebyshev-basis + MFMA GEMM, barrier-free ---------------
__global__ __launch_bounds__(256, 1) void cheby_gemm_kernel(
    const float* __restrict__ x,
    const __bf16* __restrict__ W2,
    float* __restrict__ out)
{
    const int tid  = threadIdx.x;
    const int lane = tid & 63;
    const int wid  = tid >> 6;      // 0..3
    const int wr   = wid >> 1;      // 0..1  m-half (64 rows)
    const int wc   = wid & 1;       // 0..1  n-half (128 cols)
    const int l15  = lane & 15;
    const int l4   = lane >> 4;     // 0..3
    const int bm   = blockIdx.y * 128;
    const int bn   = blockIdx.x * 256;

    // B lane base: granule (l4*DIM + bn + wc*128 + nf*16 + l15), 16B each
    const __bf16* wbase = W2 + ((size_t)l4 * DIM + bn + wc * 128 + l15) * 8;

    // x rows: bm + wr*64 + mf*16 + l15; lane's 8 i's at slot l4
    const float* xr = x + (size_t)(bm + wr * 64 + l15) * DIM + l4 * 8;

    f32x4 acc[4][8] = {};    // 128 regs (AGPR side of unified file)

    bf16x8 aone;
#pragma unroll
    for (int e = 0; e < 8; ++e) aone[e] = (__bf16)1.0f;

    // x for ic=0
    f32x4 xc[4][2];
#pragma unroll
    for (int mf = 0; mf < 4; ++mf) {
        xc[mf][0] = *reinterpret_cast<const f32x4*>(xr + mf * 16 * DIM);
        xc[mf][1] = *reinterpret_cast<const f32x4*>(xr + mf * 16 * DIM + 4);
    }

    // B register buffers: 3 rotating sets; prologue loads (k=0,ic=0) and (k=1,ic=0)
    bf16x8 bq[3][8];
#pragma unroll
    for (int nf = 0; nf < 8; ++nf)
        bq[0][nf] = *reinterpret_cast<const bf16x8*>(wbase + nf * 128);
#pragma unroll
    for (int nf = 0; nf < 8; ++nf)
        bq[1][nf] = *reinterpret_cast<const bf16x8*>(wbase + (size_t)16 * SLAB + nf * 128);

    for (int ic = 0; ic < NIC; ++ic) {
        // ---- basis init (f32): t = tanh(x) = 1 - 2/(exp2(2*log2e*x)+1) ----
        float t2[4][8], Tk[4][8], Tm[4][8];
#pragma unroll
        for (int mf = 0; mf < 4; ++mf)
#pragma unroll
            for (int e = 0; e < 8; ++e) {
                float xv = (e < 4) ? xc[mf][0][e] : xc[mf][1][e - 4];
                float p  = __builtin_amdgcn_exp2f(xv * 2.8853900817779268f);
                float t  = 1.0f - 2.0f * __builtin_amdgcn_rcpf(p + 1.0f);
                Tk[mf][e] = t;          // T_1
                t2[mf][e] = t + t;
                Tm[mf][e] = 1.0f;       // T_0
            }

        // prefetch next ic's x (latency hidden under this ic's 9 ksteps)
        f32x4 xn[4][2];
        if (ic + 1 < NIC) {
#pragma unroll
            for (int mf = 0; mf < 4; ++mf) {
                xn[mf][0] = *reinterpret_cast<const f32x4*>(xr + mf * 16 * DIM + (ic + 1) * 32);
                xn[mf][1] = *reinterpret_cast<const f32x4*>(xr + mf * 16 * DIM + (ic + 1) * 32 + 4);
            }
        }

#pragma unroll
        for (int k = 0; k < KDEG; ++k) {
            // prefetch kstep k+2 into set (k+2)%3.
            // global step index g = ic*9 + k; g%3 == k%3 since 9%3==0 -> the
            // set written here is exactly the one read 2 steps later, incl.
            // across the ic boundary (the v6/v7 parity bug).
            if ((k < KDEG - 2) || (ic + 1 < NIC)) {
                const int nk  = (k < KDEG - 2) ? k + 2 : k - 7;   // (k+2)%9
                const int nic = (k < KDEG - 2) ? ic : ic + 1;
                const __bf16* np = wbase + (size_t)(nk * 16 + nic) * SLAB;
#pragma unroll
                for (int nf = 0; nf < 8; ++nf)
                    bq[(k + 2) % 3][nf] = *reinterpret_cast<const bf16x8*>(np + nf * 128);
            }

            // A fragments for this k (f32 -> bf16 operand rounding only)
            bf16x8 af[4];
            if (k == 0) {
#pragma unroll
                for (int mf = 0; mf < 4; ++mf) af[mf] = aone;   // T_0 = 1
            } else {
#pragma unroll
                for (int mf = 0; mf < 4; ++mf)
#pragma unroll
                    for (int e = 0; e < 8; ++e)
                        af[mf][e] = (__bf16)Tk[mf][e];
            }

            // 32 MFMA (independent accumulators; uses set k%3)
#pragma unroll
            for (int nf = 0; nf < 8; ++nf)
#pragma unroll
                for (int mf = 0; mf < 4; ++mf)
                    acc[mf][nf] = __builtin_amdgcn_mfma_f32_16x16x32_bf16(
                        af[mf], bq[k % 3][nf], acc[mf][nf], 0, 0, 0);

            // advance recurrence in f32: Tn = 2t*Tk - Tm
            if (k >= 1 && k < KDEG - 1) {
#pragma unroll
                for (int mf = 0; mf < 4; ++mf)
#pragma unroll
                    for (int e = 0; e < 8; ++e) {
                        float Tn = __builtin_fmaf(t2[mf][e], Tk[mf][e], -Tm[mf][e]);
                        Tm[mf][e] = Tk[mf][e];
                        Tk[mf][e] = Tn;
                    }
            }
        }

        if (ic + 1 < NIC) {
#pragma unroll
            for (int mf = 0; mf < 4; ++mf) {
                xc[mf][0] = xn[mf][0];
                xc[mf][1] = xn[mf][1];
            }
        }
    }

    // ---- epilogue: C/D layout col=lane&15, row=(lane>>4)*4+r ----
#pragma unroll
    for (int mf = 0; mf < 4; ++mf)
#pragma unroll
        for (int r = 0; r < 4; ++r) {
            const int row = bm + wr * 64 + mf * 16 + l4 * 4 + r;
            float* orow = out + (size_t)row * DIM + bn + wc * 128 + l15;
#pragma unroll
            for (int nf = 0; nf < 8; ++nf)
                orow[nf * 16] = acc[mf][nf][r];
        }
}

extern "C" void kernel_launch(void* const* d_in, const int* in_sizes, int n_in,
                              void* d_out, int out_size, void* d_ws, size_t ws_size,
                              hipStream_t stream) {
    const float* x      = (const float*)d_in[0];   // (16384, 512)
    const float* coeffs = (const float*)d_in[1];   // (512, 512, 9)
    float* out          = (float*)d_out;           // (16384, 512)
    __bf16* W2          = (__bf16*)d_ws;           // 144*16384 bf16 = 4.7MB

    pack_w_kernel<<<(DIM * 64) / 256, 256, 0, stream>>>(coeffs, W2);

    // grid = (N/256, M/128) = (2, 128) = 256 blocks = 1/CU, 4 waves/CU, 1/SIMD.
    // bid%8 parity fixes bn per XCD -> each XCD L2 caches one 2.36MB W2 half.
    cheby_gemm_kernel<<<dim3(2, 128), 256, 0, stream>>>(x, W2, out);
}